// Round 1
// baseline (246.691 us; speedup 1.0000x reference)
//
#include <hip/hip_runtime.h>
#include <math.h>

namespace {

constexpr int H = 5;
constexpr int C = 2048;
constexpr int NPERM = 120;           // 5!
constexpr int BLOCK = 256;
constexpr int F4_PER_ROW = C / 4;    // 512 float4 per row

// One block per batch element.
__global__ __launch_bounds__(BLOCK)
void pml_per_batch(const float* __restrict__ pred,
                   const float* __restrict__ tgt,
                   float* __restrict__ ws)
{
    const int b    = blockIdx.x;
    const int t    = threadIdx.x;
    const int lane = t & 63;
    const int wv   = t >> 6;         // 4 waves per block

    __shared__ float s_wred[4];
    __shared__ int   s_wredi[4];
    __shared__ int   s_tgt[H];
    __shared__ float s_ce[H][H];     // ce[i][j] = lse_i - pred[b][i][tgt[j]]
    __shared__ float s_loss[128];

    // ---------- Phase 1: argmax over C for each target head (first occurrence) ----------
    for (int j = 0; j < H; ++j) {
        const float4* row = reinterpret_cast<const float4*>(
            tgt + ((size_t)b * H + j) * C);
        float4 v0 = row[t];
        float4 v1 = row[t + BLOCK];

        float m  = v0.x;
        int   mi = 4 * t;
        if (v0.y > m) { m = v0.y; mi = 4 * t + 1; }
        if (v0.z > m) { m = v0.z; mi = 4 * t + 2; }
        if (v0.w > m) { m = v0.w; mi = 4 * t + 3; }
        const int b1 = 4 * (t + BLOCK);
        if (v1.x > m) { m = v1.x; mi = b1;     }
        if (v1.y > m) { m = v1.y; mi = b1 + 1; }
        if (v1.z > m) { m = v1.z; mi = b1 + 2; }
        if (v1.w > m) { m = v1.w; mi = b1 + 3; }

        // wave64 argmax reduce (tie -> lowest index, matches jnp.argmax)
        #pragma unroll
        for (int off = 32; off > 0; off >>= 1) {
            float om = __shfl_down(m,  off, 64);
            int   oi = __shfl_down(mi, off, 64);
            if (om > m || (om == m && oi < mi)) { m = om; mi = oi; }
        }
        if (lane == 0) { s_wred[wv] = m; s_wredi[wv] = mi; }
        __syncthreads();
        if (t == 0) {
            float bm = s_wred[0]; int bi = s_wredi[0];
            #pragma unroll
            for (int w = 1; w < 4; ++w) {
                if (s_wred[w] > bm || (s_wred[w] == bm && s_wredi[w] < bi)) {
                    bm = s_wred[w]; bi = s_wredi[w];
                }
            }
            s_tgt[j] = bi;
        }
        __syncthreads();
    }

    // ---------- Phase 2: logsumexp per prediction head + CE matrix ----------
    for (int i = 0; i < H; ++i) {
        const size_t row_off = ((size_t)b * H + i) * C;
        const float4* row = reinterpret_cast<const float4*>(pred + row_off);
        float4 v0 = row[t];
        float4 v1 = row[t + BLOCK];

        float m = fmaxf(fmaxf(fmaxf(v0.x, v0.y), fmaxf(v0.z, v0.w)),
                        fmaxf(fmaxf(v1.x, v1.y), fmaxf(v1.z, v1.w)));
        #pragma unroll
        for (int off = 32; off > 0; off >>= 1)
            m = fmaxf(m, __shfl_down(m, off, 64));
        if (lane == 0) s_wred[wv] = m;
        __syncthreads();
        const float M = fmaxf(fmaxf(s_wred[0], s_wred[1]),
                              fmaxf(s_wred[2], s_wred[3]));

        float s = __expf(v0.x - M) + __expf(v0.y - M) +
                  __expf(v0.z - M) + __expf(v0.w - M) +
                  __expf(v1.x - M) + __expf(v1.y - M) +
                  __expf(v1.z - M) + __expf(v1.w - M);
        #pragma unroll
        for (int off = 32; off > 0; off >>= 1)
            s += __shfl_down(s, off, 64);

        __syncthreads();                 // everyone done reading s_wred (max)
        if (lane == 0) s_wred[wv] = s;
        __syncthreads();

        if (t < H) {
            const float S   = s_wred[0] + s_wred[1] + s_wred[2] + s_wred[3];
            const float lse = M + __logf(S);
            const float val = pred[row_off + s_tgt[t]];  // L1-hot, just streamed
            s_ce[i][t] = lse - val;
        }
        __syncthreads();                 // s_ce ready / protect s_wred reuse
    }

    // ---------- Phase 3: 120-permutation assignment search ----------
    float sum = INFINITY;
    if (t < NPERM) {
        // factorial-number-system decode of permutation #t (lexicographic)
        int idx = t;
        unsigned mask = 0x1Fu;
        const int fact[H] = {24, 6, 2, 1, 1};
        sum = 0.f;
        #pragma unroll
        for (int h = 0; h < H; ++h) {
            int k = idx / fact[h];
            idx -= k * fact[h];
            unsigned mm = mask;
            for (int q = 0; q < k; ++q) mm &= mm - 1;   // drop k lowest set bits
            const int p = __ffs(mm) - 1;                // k-th remaining head
            mask &= ~(1u << p);
            sum += s_ce[p][h];
        }
    }
    if (t < 128) s_loss[t] = sum;
    __syncthreads();
    #pragma unroll
    for (int st = 64; st > 0; st >>= 1) {
        if (t < st) s_loss[t] = fminf(s_loss[t], s_loss[t + st]);
        __syncthreads();
    }
    if (t == 0) ws[b] = s_loss[0] * (1.0f / H);   // min-perm mean-CE for batch b
}

// Deterministic final mean over B per-batch losses (single block).
__global__ __launch_bounds__(256)
void pml_reduce_mean(const float* __restrict__ ws, float* __restrict__ out, int B)
{
    __shared__ float s[256];
    float sum = 0.f;
    for (int i = threadIdx.x; i < B; i += 256) sum += ws[i];
    s[threadIdx.x] = sum;
    __syncthreads();
    for (int st = 128; st > 0; st >>= 1) {
        if (threadIdx.x < st) s[threadIdx.x] += s[threadIdx.x + st];
        __syncthreads();
    }
    if (threadIdx.x == 0) out[0] = s[0] / (float)B;
}

} // namespace

extern "C" void kernel_launch(void* const* d_in, const int* in_sizes, int n_in,
                              void* d_out, int out_size, void* d_ws, size_t ws_size,
                              hipStream_t stream)
{
    const float* pred = (const float*)d_in[0];
    const float* tgtp = (const float*)d_in[1];
    float* out = (float*)d_out;
    float* ws  = (float*)d_ws;

    const int B = in_sizes[0] / (H * C);   // 16384

    pml_per_batch<<<B, BLOCK, 0, stream>>>(pred, tgtp, ws);
    pml_reduce_mean<<<1, 256, 0, stream>>>(ws, out, B);
}

// Round 2
// 237.162 us; speedup vs baseline: 1.0402x; 1.0402x over previous
//
#include <hip/hip_runtime.h>
#include <math.h>

namespace {

constexpr int H     = 5;
constexpr int C     = 2048;
constexpr int NPERM = 120;      // 5!
constexpr int BLOCK = 256;
constexpr int WAVES = BLOCK / 64;

// Decode permutation p (0..119) and sum ce[perm[h]][h] via per-lane-source
// shuffles. ce lives at lane (i*5 + j) = ce[i][j]. Order of the 120 perms is
// irrelevant: only the min over all perms is used downstream.
__device__ __forceinline__ float perm_loss(int p, float ce)
{
    int idx = p;
    unsigned mask = 0x1Fu;
    float sum = 0.f;
    const int fact[H] = {24, 6, 2, 1, 1};
    #pragma unroll
    for (int h = 0; h < H; ++h) {
        const int k = idx / fact[h];
        idx -= k * fact[h];
        unsigned mm = mask;
        for (int q = 0; q < k; ++q) mm &= mm - 1;   // drop k lowest set bits
        const int ph = __ffs(mm) - 1;               // k-th remaining head
        mask &= ~(1u << ph);
        sum += __shfl(ce, ph * H + h, 64);          // all lanes participate
    }
    return sum;
}

// One wave per batch element. No LDS, no __syncthreads.
__global__ __launch_bounds__(BLOCK)
void pml_per_wave(const float* __restrict__ pred,
                  const float* __restrict__ tgt,
                  float* __restrict__ ws, int B)
{
    const int lane = threadIdx.x & 63;
    const int b    = blockIdx.x * WAVES + (threadIdx.x >> 6);
    if (b >= B) return;

    const size_t base = (size_t)b * H * C;

    // ---- Phase 1: argmax over C per target head; lane j keeps tgt_j ----
    int idx_reg = 0;
    #pragma unroll 1
    for (int j = 0; j < H; ++j) {
        const float4* row = reinterpret_cast<const float4*>(tgt + base + (size_t)j * C);
        float4 v[8];
        #pragma unroll
        for (int k = 0; k < 8; ++k) v[k] = row[lane + 64 * k];

        float m  = v[0].x;
        int   mi = 4 * lane;
        #pragma unroll
        for (int k = 0; k < 8; ++k) {
            const int e = 4 * (lane + 64 * k);
            if (v[k].x > m) { m = v[k].x; mi = e;     }
            if (v[k].y > m) { m = v[k].y; mi = e + 1; }
            if (v[k].z > m) { m = v[k].z; mi = e + 2; }
            if (v[k].w > m) { m = v[k].w; mi = e + 3; }
        }
        // butterfly argmax (tie -> lowest index, matches jnp.argmax)
        #pragma unroll
        for (int off = 32; off > 0; off >>= 1) {
            const float om = __shfl_xor(m,  off, 64);
            const int   oi = __shfl_xor(mi, off, 64);
            if (om > m || (om == m && oi < mi)) { m = om; mi = oi; }
        }
        if (lane == j) idx_reg = mi;
    }

    // ---- Phase 2: logsumexp per prediction head; lane i keeps lse_i ----
    float lse_reg = 0.f;
    #pragma unroll 1
    for (int i = 0; i < H; ++i) {
        const float4* row = reinterpret_cast<const float4*>(pred + base + (size_t)i * C);
        float4 v[8];
        #pragma unroll
        for (int k = 0; k < 8; ++k) v[k] = row[lane + 64 * k];

        float m = -INFINITY;
        #pragma unroll
        for (int k = 0; k < 8; ++k)
            m = fmaxf(m, fmaxf(fmaxf(v[k].x, v[k].y), fmaxf(v[k].z, v[k].w)));
        #pragma unroll
        for (int off = 32; off > 0; off >>= 1)
            m = fmaxf(m, __shfl_xor(m, off, 64));

        float s = 0.f;
        #pragma unroll
        for (int k = 0; k < 8; ++k)
            s += __expf(v[k].x - m) + __expf(v[k].y - m) +
                 __expf(v[k].z - m) + __expf(v[k].w - m);
        #pragma unroll
        for (int off = 32; off > 0; off >>= 1)
            s += __shfl_xor(s, off, 64);

        const float lse = m + __logf(s);
        if (lane == i) lse_reg = lse;
    }

    // ---- CE matrix: lane (i*5+j) holds ce[i][j] = lse_i - pred[b,i,tgt_j] ----
    float ce = 0.f;
    {
        const int i  = lane / 5;
        const int j  = lane - 5 * i;
        const int tj = __shfl(idx_reg, j, 64);      // uniform participation
        const float li = __shfl(lse_reg, i, 64);
        if (lane < 25)
            ce = li - pred[base + (size_t)i * C + tj];
    }

    // ---- 120-permutation search: 2 perms per lane, wave min-reduce ----
    const float l0 = perm_loss(lane, ce);
    const int   p2 = lane + 64;
    float       l1 = perm_loss(p2 < NPERM ? p2 : 0, ce);
    if (p2 >= NPERM) l1 = INFINITY;

    float best = fminf(l0, l1);
    #pragma unroll
    for (int off = 32; off > 0; off >>= 1)
        best = fminf(best, __shfl_xor(best, off, 64));

    if (lane == 0) ws[b] = best * (1.0f / H);
}

// Deterministic final mean over B per-batch losses (single block).
__global__ __launch_bounds__(1024)
void pml_reduce_mean(const float* __restrict__ ws, float* __restrict__ out, int B)
{
    __shared__ float s[1024];
    float sum = 0.f;
    for (int i = threadIdx.x; i < B; i += 1024) sum += ws[i];
    s[threadIdx.x] = sum;
    __syncthreads();
    for (int st = 512; st > 0; st >>= 1) {
        if (threadIdx.x < st) s[threadIdx.x] += s[threadIdx.x + st];
        __syncthreads();
    }
    if (threadIdx.x == 0) out[0] = s[0] / (float)B;
}

} // namespace

extern "C" void kernel_launch(void* const* d_in, const int* in_sizes, int n_in,
                              void* d_out, int out_size, void* d_ws, size_t ws_size,
                              hipStream_t stream)
{
    const float* pred = (const float*)d_in[0];
    const float* tgtp = (const float*)d_in[1];
    float* out = (float*)d_out;
    float* ws  = (float*)d_ws;

    const int B = in_sizes[0] / (H * C);   // 16384

    const int grid = (B + WAVES - 1) / WAVES;
    pml_per_wave<<<grid, BLOCK, 0, stream>>>(pred, tgtp, ws, B);
    pml_reduce_mean<<<1, 1024, 0, stream>>>(ws, out, B);
}

// Round 4
// 211.085 us; speedup vs baseline: 1.1687x; 1.1235x over previous
//
#include <hip/hip_runtime.h>
#include <math.h>

namespace {

constexpr int H     = 5;
constexpr int C     = 2048;
constexpr int NPERM = 120;      // 5!
constexpr int BLOCK = 256;
constexpr int WAVES = BLOCK / 64;

typedef float f32x4 __attribute__((ext_vector_type(4)));   // native vector: NT-load legal

__device__ __forceinline__ void load_row(f32x4 (&buf)[8], const float* __restrict__ p, int lane)
{
    const f32x4* r = reinterpret_cast<const f32x4*>(p);
    #pragma unroll
    for (int k = 0; k < 8; ++k) buf[k] = r[lane + 64 * k];
}

// Non-temporal variant: targets are read-once, dead after argmax — keep them
// out of L2 so streamed pred rows stay warm for the CE gather.
__device__ __forceinline__ void load_row_nt(f32x4 (&buf)[8], const float* __restrict__ p, int lane)
{
    const f32x4* r = reinterpret_cast<const f32x4*>(p);
    #pragma unroll
    for (int k = 0; k < 8; ++k) buf[k] = __builtin_nontemporal_load(&r[lane + 64 * k]);
}

// argmax over one target row; lane j latches the winning class index.
__device__ __forceinline__ void proc_tgt(const f32x4 (&v)[8], int j, int lane, int& idx_reg)
{
    float m  = v[0].x;
    int   mi = 4 * lane;
    #pragma unroll
    for (int k = 0; k < 8; ++k) {
        const int e = 4 * (lane + 64 * k);
        if (v[k].x > m) { m = v[k].x; mi = e;     }
        if (v[k].y > m) { m = v[k].y; mi = e + 1; }
        if (v[k].z > m) { m = v[k].z; mi = e + 2; }
        if (v[k].w > m) { m = v[k].w; mi = e + 3; }
    }
    #pragma unroll
    for (int off = 32; off > 0; off >>= 1) {     // tie -> lowest index (jnp.argmax)
        const float om = __shfl_xor(m,  off, 64);
        const int   oi = __shfl_xor(mi, off, 64);
        if (om > m || (om == m && oi < mi)) { m = om; mi = oi; }
    }
    if (lane == j) idx_reg = mi;
}

// logsumexp over one prediction row; lane i latches lse_i.
__device__ __forceinline__ void proc_pred(const f32x4 (&v)[8], int i, int lane, float& lse_reg)
{
    float m = -INFINITY;
    #pragma unroll
    for (int k = 0; k < 8; ++k)
        m = fmaxf(m, fmaxf(fmaxf(v[k].x, v[k].y), fmaxf(v[k].z, v[k].w)));
    #pragma unroll
    for (int off = 32; off > 0; off >>= 1)
        m = fmaxf(m, __shfl_xor(m, off, 64));

    float s = 0.f;
    #pragma unroll
    for (int k = 0; k < 8; ++k)
        s += __expf(v[k].x - m) + __expf(v[k].y - m) +
             __expf(v[k].z - m) + __expf(v[k].w - m);
    #pragma unroll
    for (int off = 32; off > 0; off >>= 1)
        s += __shfl_xor(s, off, 64);

    if (lane == i) lse_reg = m + __logf(s);
}

// Decode permutation p (0..119), sum ce[perm[h]][h] via per-lane-source
// shuffles; ce lives at lane (i*5 + j). Perm enumeration order is irrelevant
// (only the min survives).
__device__ __forceinline__ float perm_loss(int p, float ce)
{
    int idx = p;
    unsigned mask = 0x1Fu;
    float sum = 0.f;
    const int fact[H] = {24, 6, 2, 1, 1};
    #pragma unroll
    for (int h = 0; h < H; ++h) {
        const int k = idx / fact[h];
        idx -= k * fact[h];
        unsigned mm = mask;
        for (int q = 0; q < k; ++q) mm &= mm - 1;   // drop k lowest set bits
        const int ph = __ffs(mm) - 1;               // k-th remaining head
        mask &= ~(1u << ph);
        sum += __shfl(ce, ph * H + h, 64);
    }
    return sum;
}

// One wave per batch element. No LDS, no __syncthreads. Row loads are
// software-pipelined through two statically-named buffers (rule: no
// runtime-indexed register arrays) so each wave keeps 8 global loads in
// flight while reducing the previous row.
__global__ __launch_bounds__(BLOCK)
void pml_per_wave(const float* __restrict__ pred,
                  const float* __restrict__ tgt,
                  float* __restrict__ ws, int B)
{
    const int lane = threadIdx.x & 63;
    const int b    = blockIdx.x * WAVES + (threadIdx.x >> 6);
    if (b >= B) return;

    const size_t base = (size_t)b * H * C;
    const float* tp = tgt  + base;
    const float* pp = pred + base;

    int   idx_reg = 0;   // lane j holds tgt argmax of head j (j<5)
    float lse_reg = 0.f; // lane i holds lse of pred head i   (i<5)

    f32x4 A[8], Bv[8];

    // ---- pipelined 10-row stream: rows 0-4 = tgt (NT), rows 5-9 = pred ----
    load_row_nt(A,  tp,         lane);
    load_row_nt(Bv, tp + C,     lane);
    proc_tgt (A,  0, lane, idx_reg);
    load_row_nt(A,  tp + 2 * C, lane);
    proc_tgt (Bv, 1, lane, idx_reg);
    load_row_nt(Bv, tp + 3 * C, lane);
    proc_tgt (A,  2, lane, idx_reg);
    load_row_nt(A,  tp + 4 * C, lane);
    proc_tgt (Bv, 3, lane, idx_reg);
    load_row  (Bv, pp,          lane);
    proc_tgt (A,  4, lane, idx_reg);
    load_row  (A,  pp + C,      lane);
    proc_pred(Bv, 0, lane, lse_reg);
    load_row  (Bv, pp + 2 * C,  lane);
    proc_pred(A,  1, lane, lse_reg);
    load_row  (A,  pp + 3 * C,  lane);
    proc_pred(Bv, 2, lane, lse_reg);
    load_row  (Bv, pp + 4 * C,  lane);
    proc_pred(A,  3, lane, lse_reg);
    proc_pred(Bv, 4, lane, lse_reg);

    // ---- CE matrix: lane (i*5+j) holds ce[i][j] = lse_i - pred[b,i,tgt_j] ----
    float ce = 0.f;
    {
        const int i  = lane / 5;
        const int j  = lane - 5 * i;
        const int   tj = __shfl(idx_reg, j, 64);
        const float li = __shfl(lse_reg, i, 64);
        if (lane < 25)
            ce = li - pp[(size_t)i * C + tj];   // L2/L3-warm gather
    }

    // ---- 120-permutation search: 2 perms per lane, wave min-reduce ----
    const float l0 = perm_loss(lane, ce);
    const int   p2 = lane + 64;
    float       l1 = perm_loss(p2 < NPERM ? p2 : 0, ce);
    if (p2 >= NPERM) l1 = INFINITY;

    float best = fminf(l0, l1);
    #pragma unroll
    for (int off = 32; off > 0; off >>= 1)
        best = fminf(best, __shfl_xor(best, off, 64));

    if (lane == 0) ws[b] = best * (1.0f / H);
}

// Deterministic final mean over B per-batch losses (single block).
__global__ __launch_bounds__(1024)
void pml_reduce_mean(const float* __restrict__ ws, float* __restrict__ out, int B)
{
    __shared__ float s[1024];
    float sum = 0.f;
    for (int i = threadIdx.x; i < B; i += 1024) sum += ws[i];
    s[threadIdx.x] = sum;
    __syncthreads();
    for (int st = 512; st > 0; st >>= 1) {
        if (threadIdx.x < st) s[threadIdx.x] += s[threadIdx.x + st];
        __syncthreads();
    }
    if (threadIdx.x == 0) out[0] = s[0] / (float)B;
}

} // namespace

extern "C" void kernel_launch(void* const* d_in, const int* in_sizes, int n_in,
                              void* d_out, int out_size, void* d_ws, size_t ws_size,
                              hipStream_t stream)
{
    const float* pred = (const float*)d_in[0];
    const float* tgtp = (const float*)d_in[1];
    float* out = (float*)d_out;
    float* ws  = (float*)d_ws;

    const int B = in_sizes[0] / (H * C);   // 16384

    const int grid = (B + WAVES - 1) / WAVES;
    pml_per_wave<<<grid, BLOCK, 0, stream>>>(pred, tgtp, ws, B);
    pml_reduce_mean<<<1, 1024, 0, stream>>>(ws, out, B);
}